// Round 13
// baseline (485.668 us; speedup 1.0000x reference)
//
#include <hip/hip_runtime.h>
#include <hip/hip_cooperative_groups.h>
#include <hip/hip_fp16.h>
#include <math.h>

namespace cg = cooperative_groups;

#define BB 2
#define CC 64
#define NN 16384
#define DD 3
#define KK 128
#define EE 262144
#define GG 3
#define PP2 64           // k_a units per (b): 64 chunk2 x 4 kt
#define KTOT 576         // concat K: 256 interleaved cos/sin + 64 x + 64 h + 192 gradf

typedef short bf16x8 __attribute__((ext_vector_type(8)));
typedef float f32x4  __attribute__((ext_vector_type(4)));

__device__ __forceinline__ short f2bf(float f) {
    unsigned u = __float_as_uint(f);
    u += 0x7FFF + ((u >> 16) & 1);          // round-to-nearest-even
    return (short)(u >> 16);
}
__device__ __forceinline__ float bf2f(unsigned short u) {
    return __uint_as_float(((unsigned)u) << 16);
}

// ---- workspace layout (float elements) ----
constexpr size_t OFF_XB   = 0;                                  // bf16 xB[b][n][64]
constexpr size_t OFF_PC   = OFF_XB   + (size_t)BB*NN*32;        // fp32 partial A_c
constexpr size_t OFF_PS   = OFF_PC   + (size_t)BB*128*CC*KK;    // fp32 partial A_s
constexpr size_t OFF_BIN4 = OFF_PC;                             // float4 binlist[b][E] (aliases pc)
constexpr size_t OFF_AC   = OFF_PS   + (size_t)BB*128*CC*KK;    // A_c[b][i][k]
constexpr size_t OFF_AS   = OFF_AC   + (size_t)BB*CC*KK;
constexpr size_t OFF_F0   = OFF_AS   + (size_t)BB*CC*KK;        // f0[b][o]
constexpr size_t OFF_X0   = OFF_F0   + (size_t)BB*CC;           // x0[b][i]
constexpr size_t OFF_CNT  = OFF_X0   + (size_t)BB*CC;           // int counts (zeroed)
constexpr size_t OFF_OFFS = OFF_CNT  + (size_t)BB*NN;           // int offsets
constexpr size_t OFF_RANK = OFF_OFFS + (size_t)BB*NN;           // int rank[b][E]
constexpr size_t OFF_GRB  = OFF_RANK + (size_t)BB*EE;           // (unused)
constexpr size_t OFF_APAN = OFF_GRB  + (size_t)BB*NN*96;        // bf16 ApanT[b][64 o][576 k]
constexpr size_t OFF_GWXT = OFF_APAN + (size_t)BB*KTOT*CC/2;    // geo_wx^T [g][i] (fp32)

// phase-1 unit counts (512-thread units)
#define U_KA  (BB*PP2*4)          // 512
#define U_ED  ((BB*EE)/512)       // 1024
#define U_TR  (BB*(NN/64))        // 512
#define U_X0  (BB*CC)             // 128
#define U_WT  24
#define U1 (U_KA + U_ED + U_TR + U_X0 + U_WT)   // 2200
#define U2 (512 + BB)             // 514
#define U3 (BB*CC + (BB*EE)/512)  // 128 + 1024
#define U4 (BB*(NN/32))           // 1024

__global__ void __launch_bounds__(512, 8)
mega(const float* __restrict__ x, const float* __restrict__ nwt,
     const int* __restrict__ edges, const float* __restrict__ egw,
     const float* __restrict__ W, const float* __restrict__ gw,
     const float* __restrict__ geo_wx, const float* __restrict__ w2,
     const float* __restrict__ nodes, const float* __restrict__ modes,
     const float* __restrict__ geo, const float* __restrict__ wcw,
     const float* __restrict__ wsw, const float* __restrict__ w0,
     const float* __restrict__ wx,
     unsigned short* __restrict__ xB, float* __restrict__ x0v,
     int* __restrict__ counts, int* __restrict__ rank,
     float* __restrict__ gwxT, short* __restrict__ ApanB,
     float* __restrict__ pc, float* __restrict__ ps,
     float* __restrict__ Ac, float* __restrict__ As_,
     float* __restrict__ f0, int* __restrict__ offsets,
     float4* __restrict__ bin4, float* __restrict__ out) {
    cg::grid_group gridg = cg::this_grid();
    int NB = gridDim.x;
    int tid = threadIdx.x;
    int lane = tid & 63;
    int w = tid >> 6;                  // 0..7
    __shared__ __align__(16) char smem[37776];

    // ================= phase 1: pre-pass + spectral partials =================
    for (int u = blockIdx.x; u < U1; u += NB) {
        __syncthreads();               // LDS reuse guard between units
        if (u < U_KA) {
            // ---- spectral partials (k_a): 8 waves, 1 i-tile each ----
            short* Axw = (short*)smem;                     // [64][136]
            short* Bc  = (short*)(smem + 17408);           // [32][136]
            short* Bsn = (short*)(smem + 17408 + 8704);    // [32][136]
            float* ndl = (float*)(smem + 17408 + 8704 + 8704);  // 384 f
            int b = u >> 8;
            int rem = u & 255;
            int chunk2 = rem >> 2;
            int kt = rem & 3;
            int k0 = kt * 32;
            int col = lane & 15;
            int quad = lane >> 4;
            int wk = w & 1;            // k half
            int wi = w >> 1;           // i-tile 0..3
            f32x4 ac, as4;
#pragma unroll
            for (int r = 0; r < 4; r++) { ac[r] = 0.f; as4[r] = 0.f; }
            for (int h = 0; h < 2; h++) {
                int nbase = chunk2*256 + h*128;
                if (h) __syncthreads();
                for (int e = tid; e < 384; e += 512) ndl[e] = nodes[((size_t)b*NN + nbase)*3 + e];
#pragma unroll
                for (int s = 0; s < 4; s++) {
                    int e = tid + s*512;
                    int i = e >> 5, seg = e & 31;
                    float4 xv = *(const float4*)&x[((size_t)b*CC + i)*NN + nbase + seg*4];
                    float4 wv = *(const float4*)&nwt[(size_t)b*NN + nbase + seg*4];
                    unsigned lo = (unsigned)(unsigned short)f2bf(xv.x*wv.x)
                                | ((unsigned)(unsigned short)f2bf(xv.y*wv.y) << 16);
                    unsigned hi = (unsigned)(unsigned short)f2bf(xv.z*wv.z)
                                | ((unsigned)(unsigned short)f2bf(xv.w*wv.w) << 16);
                    *(uint2*)&Axw[i*136 + seg*4] = make_uint2(lo, hi);
                }
                __syncthreads();
#pragma unroll
                for (int s = 0; s < 8; s++) {
                    int e = tid + s*512;
                    int n = e & 127, kl = e >> 7;
                    int k = k0 + kl;
                    float t = ndl[n*3+0]*modes[k*3+0] + ndl[n*3+1]*modes[k*3+1]
                            + ndl[n*3+2]*modes[k*3+2];
                    Bc [kl*136 + n] = f2bf(__cosf(t));
                    Bsn[kl*136 + n] = f2bf(__sinf(t));
                }
                __syncthreads();
                int rowB = (wk*16 + col)*136;
#pragma unroll
                for (int ns = 0; ns < 4; ns++) {
                    int koff = ns*32 + quad*8;
                    bf16x8 bcf = *(bf16x8*)&Bc [rowB + koff];
                    bf16x8 bsf = *(bf16x8*)&Bsn[rowB + koff];
                    bf16x8 af = *(bf16x8*)&Axw[(wi*16 + col)*136 + koff];
                    ac  = __builtin_amdgcn_mfma_f32_16x16x32_bf16(af, bcf, ac, 0, 0, 0);
                    as4 = __builtin_amdgcn_mfma_f32_16x16x32_bf16(af, bsf, as4, 0, 0, 0);
                }
            }
            int base = (b*PP2 + chunk2)*CC;
            int kw = k0 + wk*16 + col;
#pragma unroll
            for (int r = 0; r < 4; r++) {
                int i = wi*16 + quad*4 + r;
                pc[(size_t)(base + i)*KK + kw] = ac[r];
                ps[(size_t)(base + i)*KK + kw] = as4[r];
            }
        } else if (u < U_KA + U_ED) {
            // ---- edge count + rank ----
            int idx = (u - U_KA)*512 + tid;
            int tgt = edges[(size_t)idx*2 + 0];
            int b = idx / EE;
            rank[idx] = atomicAdd(&counts[b*NN + tgt], 1);
        } else if (u < U_KA + U_ED + U_TR) {
            // ---- transpose x -> xB bf16 ----
            float (*tile)[65] = (float (*)[65])smem;
            int tb = u - (U_KA + U_ED);
            int b = tb / (NN/64);
            int n0 = (tb % (NN/64)) * 64;
            int c = tid & 63, r8 = tid >> 6;
            for (int rr = 0; rr < 8; rr++) {
                int i = r8*8 + rr;
                tile[i][c] = x[((size_t)b*CC + i)*NN + n0 + c];
            }
            __syncthreads();
            for (int rr = 0; rr < 8; rr++) {
                int nn = r8*8 + rr;
                xB[((size_t)b*NN + n0 + nn)*64 + c] = (unsigned short)f2bf(tile[c][nn]);
            }
        } else if (u < U_KA + U_ED + U_TR + U_X0) {
            // ---- x0 reduction ----
            float* red = (float*)smem;
            int bi = u - (U_KA + U_ED + U_TR);
            int b = bi >> 6, i = bi & 63;
            const float4* __restrict__ xr = (const float4*)&x[((size_t)b*CC + i)*NN];
            const float4* __restrict__ wr = (const float4*)&nwt[(size_t)b*NN];
            float s = 0.f;
            for (int t = tid; t < NN/4; t += 512) {
                float4 xv = xr[t];
                float4 wv = wr[t];
                s += xv.x*wv.x + xv.y*wv.y + xv.z*wv.z + xv.w*wv.w;
            }
            red[tid] = s;
            __syncthreads();
            for (int off = 256; off > 0; off >>= 1) {
                if (tid < off) red[tid] += red[tid+off];
                __syncthreads();
            }
            if (tid == 0) x0v[b*CC + i] = red[0];
        } else {
            // ---- weights prep ----
            int idx = (u - (U_KA + U_ED + U_TR + U_X0))*512 + tid;
            if (idx < CC*CC) {
                int j = idx>>6, o = idx&63;
                short wv  = f2bf(W[o*CC+j]);
                short w2v = f2bf(w2[o*CC+j]);
                ApanB[((size_t)(0*CC+o))*KTOT + 256 + j] = wv;
                ApanB[((size_t)(1*CC+o))*KTOT + 256 + j] = wv;
                ApanB[((size_t)(0*CC+o))*KTOT + 320 + j] = w2v;
                ApanB[((size_t)(1*CC+o))*KTOT + 320 + j] = w2v;
            }
            if (idx < CC*CC*DD) {
                int g = idx>>6, o = idx&63;
                short gv = f2bf(gw[o*(CC*DD)+g]);
                ApanB[((size_t)(0*CC+o))*KTOT + 384 + g] = gv;
                ApanB[((size_t)(1*CC+o))*KTOT + 384 + g] = gv;
            }
            if (idx < GG*CC) { int g = idx>>6, i = idx&63; gwxT[idx] = geo_wx[i*GG+g]; }
        }
    }
    gridg.sync();

    // ================= phase 2: partial reduction + count scan =================
    for (int u = blockIdx.x; u < U2; u += NB) {
        __syncthreads();
        if (u < 512) {
            int idx = u*32 + (tid >> 4);        // [0, 16384)
            int sub = tid & 15;
            int b = idx / (CC*KK);
            int r = idx % (CC*KK);
            float sc = 0.f, ss = 0.f;
            for (int ch = sub; ch < PP2; ch += 16) {
                size_t o = ((size_t)(b*PP2 + ch)*CC)*KK + r;
                sc += pc[o]; ss += ps[o];
            }
            sc += __shfl_xor(sc, 1); sc += __shfl_xor(sc, 2);
            sc += __shfl_xor(sc, 4); sc += __shfl_xor(sc, 8);
            ss += __shfl_xor(ss, 1); ss += __shfl_xor(ss, 2);
            ss += __shfl_xor(ss, 4); ss += __shfl_xor(ss, 8);
            if (sub == 0) { Ac[idx] = sc; As_[idx] = ss; }
        } else {
            // exclusive scan of counts -> offsets (512 thr x 32 nodes)
            int b = u - 512;
            int* part = (int*)smem;
            int base = b*NN + tid*32;
            int s = 0;
            for (int j = 0; j < 32; j++) s += counts[base + j];
            part[tid] = s;
            __syncthreads();
            for (int off = 1; off < 512; off <<= 1) {
                int v = (tid >= off) ? part[tid - off] : 0;
                __syncthreads();
                part[tid] += v;
                __syncthreads();
            }
            int excl = part[tid] - s;
            for (int j = 0; j < 32; j++) {
                int c = counts[base + j];
                offsets[base + j] = excl;
                excl += c;
            }
        }
    }
    gridg.sync();

    // ================= phase 3: channel mix + bin fill =================
    for (int u = blockIdx.x; u < U3; u += NB) {
        __syncthreads();
        if (u < BB*CC) {
            // ---- mix: unit = (b, o), 512 thr = 2 khalves x 256 ----
            float* rc  = (float*)smem;            // [512]
            float* rs  = (float*)(smem + 2048);   // [512]
            float* f0s = (float*)(smem + 4096);   // [64]
            int b = u >> 6, o = u & 63;
            int khalf = tid >> 8;
            int t2 = tid & 255;
            int kl = t2 & 63, ig = t2 >> 6;
            int k = khalf*64 + kl;
            float fc = 0.f, fs = 0.f;
            for (int ii = 0; ii < 16; ii++) {
                int i = ig*16 + ii;
                float a_c = Ac[(b*CC+i)*KK + k];
                float a_s = As_[(b*CC+i)*KK + k];
                float wcc = wcw[((size_t)(i*CC+o))*KK + k];
                float wss = wsw[((size_t)(i*CC+o))*KK + k];
                fc += a_c*wcc + a_s*wss;
                fs += a_c*wss - a_s*wcc;
            }
            rc[tid] = fc; rs[tid] = fs;
            if (tid < 64) f0s[tid] = x0v[b*CC + tid] * w0[tid*CC + o];
            __syncthreads();
            if (ig == 0) {
                int tb = khalf*256;
                fc = rc[tb+kl] + rc[tb+64+kl] + rc[tb+128+kl] + rc[tb+192+kl];
                fs = rs[tb+kl] + rs[tb+64+kl] + rs[tb+128+kl] + rs[tb+192+kl];
                unsigned pk = (unsigned)(unsigned short)f2bf(2.f*fc)
                            | ((unsigned)(unsigned short)f2bf(-2.f*fs) << 16);
                ((unsigned*)ApanB)[((size_t)(b*CC + o))*(KTOT/2) + k] = pk;
            }
            if (tid == 0) {
                float acc2 = 0.f;
                for (int i = 0; i < 64; i++) acc2 += f0s[i];
                f0[b*CC+o] = acc2;
            }
        } else {
            // ---- bin fill (atomic-free: rank precomputed) ----
            int e = (u - BB*CC)*512 + tid;
            int b = e / EE;
            int tgt = edges[(size_t)e*2+0];
            int src = edges[(size_t)e*2+1];
            const float* __restrict__ ew = &egw[(size_t)e*3];
            float e0 = ew[0], e1 = ew[1], e2 = ew[2];
            int pos = offsets[b*NN+tgt] + rank[e];
            bin4[(size_t)b*EE + pos] = make_float4(__int_as_float(src), e0, e1, e2);
        }
    }
    gridg.sync();

    // ================= phase 4: edge accumulate + final MFMA GEMM =================
    {
        short* As = (short*)smem;                         // [64][72]
        short* Bs = (short*)(smem + 9216);                // [32][72]
        short* Ws = (short*)(smem + 13824);               // [64][72]
        unsigned short* gradfL = (unsigned short*)(smem + 23040); // [3][32][72]
        float* ndl  = (float*)(smem + 36864);             // [96]
        float* geo3 = (float*)(smem + 37248);             // [96]
        int* soff   = (int*)(smem + 37632);               // [33]
        int wr = w >> 1;
        int wc = w & 1;
        int col  = lane & 15;
        int quad = lane >> 4;
        int quad8 = quad * 8;
        int quad4 = quad * 4;
        for (int u = blockIdx.x; u < U4; u += NB) {
            __syncthreads();
            int b  = u >> 9;
            int n0 = (u & 511) * 32;
            if (tid < 96) ndl[tid]  = nodes[((size_t)b*NN + n0)*3 + tid];
            if (tid < 96) geo3[tid] = geo[((size_t)b*GG + (tid >> 5))*NN + n0 + (tid & 31)];
            if (tid >= 128 && tid < 161) {
                int idx = n0 + tid - 128;
                soff[tid - 128] = (idx < NN) ? offsets[b*NN + idx] : EE;
            }
            for (int e = tid; e < 4096; e += 512) {
                int i = e >> 6, j = e & 63;
                Ws[i*72 + j] = f2bf(wx[i*64 + j]);
            }
            f32x4 acc, xwa;
#pragma unroll
            for (int r = 0; r < 4; r++) { acc[r] = f0[b*CC + wr*16 + quad4 + r]; xwa[r] = 0.f; }
            __syncthreads();

            const unsigned short* __restrict__ xBb = xB + (size_t)b*NN*64 + lane;
            const float4* __restrict__ binb = bin4 + (size_t)b*EE;
            for (int q = 0; q < 4; q++) {
                int nl = w*4 + q;
                int js = soff[nl], je = soff[nl+1];
                float a0 = 0.f, a1 = 0.f, a2 = 0.f, s0 = 0.f, s1 = 0.f, s2 = 0.f;
#pragma unroll 4
                for (int j = js; j < je; j++) {
                    float4 e = binb[j];
                    int src = __float_as_int(e.x);
                    float xs = bf2f(xBb[(size_t)src*64]);
                    a0 = fmaf(xs, e.y, a0);
                    a1 = fmaf(xs, e.z, a1);
                    a2 = fmaf(xs, e.w, a2);
                    s0 += e.y; s1 += e.z; s2 += e.w;
                }
                float xtgt = bf2f(xBb[(size_t)(n0 + nl)*64]);
                float fv0 = a0 - xtgt*s0;
                float fv1 = a1 - xtgt*s1;
                float fv2 = a2 - xtgt*s2;
                int g0 = lane*3;
                gradfL[(g0>>6)*2304 + nl*72 + (g0&63)] = (unsigned short)f2bf(fv0);
                int g1 = g0 + 1;
                gradfL[(g1>>6)*2304 + nl*72 + (g1&63)] = (unsigned short)f2bf(fv1);
                int g2 = g0 + 2;
                gradfL[(g2>>6)*2304 + nl*72 + (g2&63)] = (unsigned short)f2bf(fv2);
            }

            const short* __restrict__ Ab = ApanB + ((size_t)b*CC)*KTOT;
            for (int c = 0; c < 9; c++) {
                __syncthreads();
                {
                    int o = tid >> 3, seg = tid & 7;
                    *(uint4*)&As[o*72 + seg*8] =
                        *(const uint4*)&Ab[(size_t)o*KTOT + c*64 + seg*8];
                }
                if (c < 4) {
#pragma unroll
                    for (int s = 0; s < 2; s++) {
                        int e = tid + s*512;
                        int n = e >> 5, kpl = e & 31;
                        int kp = c*32 + kpl;
                        float t = ndl[n*3+0]*modes[kp*3+0] + ndl[n*3+1]*modes[kp*3+1]
                                + ndl[n*3+2]*modes[kp*3+2];
                        unsigned pk = (unsigned)(unsigned short)f2bf(__cosf(t))
                                    | ((unsigned)(unsigned short)f2bf(__sinf(t)) << 16);
                        ((unsigned*)Bs)[n*36 + kpl] = pk;
                    }
                } else if (c == 4) {
                    if (tid < 256) {
                        int n = tid >> 3, seg = tid & 7;
                        *(uint4*)&Bs[n*72 + seg*8] =
                            *(const uint4*)&xB[((size_t)(b*NN + n0 + n))*64 + seg*8];
                    }
                } else if (c == 5) {
                    int n = wc*16 + col;
                    float gv0 = geo3[n], gv1 = geo3[32+n], gv2 = geo3[64+n];
#pragma unroll
                    for (int r = 0; r < 4; r++) {
                        int i = wr*16 + quad4 + r;
                        float t = gwxT[i]*gv0 + gwxT[64+i]*gv1 + gwxT[128+i]*gv2;
                        float ssv = t / (1.f + fabsf(t));
                        Bs[n*72 + i] = f2bf(ssv * xwa[r]);
                    }
                }
                __syncthreads();
                const short* Bbase = (c >= 6) ? (const short*)&gradfL[(size_t)(c-6)*2304] : Bs;
                int rowA = (wr*16 + col) * 72;
                int rowB = (wc*16 + col) * 72;
#pragma unroll
                for (int ko = 0; ko < 2; ko++) {
                    int koff = ko*32 + quad8;
                    bf16x8 af = *(bf16x8*)&As[rowA + koff];
                    bf16x8 bfv = *(bf16x8*)&Bbase[rowB + koff];
                    acc = __builtin_amdgcn_mfma_f32_16x16x32_bf16(af, bfv, acc, 0, 0, 0);
                    if (c == 4) {
                        bf16x8 wf = *(bf16x8*)&Ws[rowA + koff];
                        xwa = __builtin_amdgcn_mfma_f32_16x16x32_bf16(wf, bfv, xwa, 0, 0, 0);
                    }
                }
            }
#pragma unroll
            for (int r = 0; r < 4; r++) {
                int o = wr*16 + quad4 + r;
                float v = acc[r];
                float g = 0.5f * v * (1.f + erff(v * 0.70710678118654752f));
                out[((size_t)b*CC + o)*NN + n0 + wc*16 + col] = g;
            }
        }
    }
}

extern "C" void kernel_launch(void* const* d_in, const int* in_sizes, int n_in,
                              void* d_out, int out_size, void* d_ws, size_t ws_size,
                              hipStream_t stream) {
    const float* x      = (const float*)d_in[0];
    const float* nodes  = (const float*)d_in[1];
    const float* nwt    = (const float*)d_in[2];
    const float* geo    = (const float*)d_in[3];
    const int*   edges  = (const int*)d_in[4];
    const float* egw    = (const float*)d_in[5];
    const float* modes  = (const float*)d_in[6];
    const float* wcw    = (const float*)d_in[7];
    const float* wsw    = (const float*)d_in[8];
    const float* w0     = (const float*)d_in[9];
    const float* W      = (const float*)d_in[10];
    const float* gw     = (const float*)d_in[11];
    const float* geo_wx = (const float*)d_in[12];
    const float* wx     = (const float*)d_in[13];
    const float* w2     = (const float*)d_in[14];

    float* ws   = (float*)d_ws;
    unsigned short* xB  = (unsigned short*)(ws + OFF_XB);
    float* pc   = ws + OFF_PC;
    float* ps   = ws + OFF_PS;
    float* Ac   = ws + OFF_AC;
    float* As_  = ws + OFF_AS;
    float* f0   = ws + OFF_F0;
    float* x0v  = ws + OFF_X0;
    int*  counts = (int*)(ws + OFF_CNT);
    int*  offs   = (int*)(ws + OFF_OFFS);
    int*  rank   = (int*)(ws + OFF_RANK);
    float4* bin4 = (float4*)(ws + OFF_BIN4);
    short* ApanB  = (short*)(ws + OFF_APAN);
    float* gwxT   = ws + OFF_GWXT;
    float* out  = (float*)d_out;

    hipMemsetAsync(counts, 0, (size_t)(BB*NN)*sizeof(int), stream);

    static int s_nb = 0;
    if (s_nb == 0) {
        int bpc = 0;
        hipError_t err = hipOccupancyMaxActiveBlocksPerMultiprocessor(
            &bpc, (const void*)mega, 512, 0);
        if (err != hipSuccess || bpc < 1) bpc = 1;
        s_nb = bpc * 256;                 // 256 CUs on MI355X
        if (s_nb > 1024) s_nb = 1024;
        if (s_nb < 1) s_nb = 1;
    }

    void* args[] = {
        (void*)&x, (void*)&nwt, (void*)&edges, (void*)&egw,
        (void*)&W, (void*)&gw, (void*)&geo_wx, (void*)&w2,
        (void*)&nodes, (void*)&modes, (void*)&geo, (void*)&wcw,
        (void*)&wsw, (void*)&w0, (void*)&wx,
        (void*)&xB, (void*)&x0v, (void*)&counts, (void*)&rank,
        (void*)&gwxT, (void*)&ApanB, (void*)&pc, (void*)&ps,
        (void*)&Ac, (void*)&As_, (void*)&f0, (void*)&offs,
        (void*)&bin4, (void*)&out
    };
    hipLaunchCooperativeKernel((const void*)mega, dim3(s_nb), dim3(512),
                               args, 0, stream);
}

// Round 14
// 181.335 us; speedup vs baseline: 2.6783x; 2.6783x over previous
//
#include <hip/hip_runtime.h>
#include <hip/hip_fp16.h>
#include <math.h>

#define BB 2
#define CC 64
#define NN 16384
#define DD 3
#define KK 128
#define EE 262144
#define GG 3
#define PP 128           // n-chunks of 128 (geometry)
#define PP2 64           // partial-chunks: 2 n-chunks accumulated per k_a block
#define LL (NN/PP)       // 128 n per chunk
#define KTOT 576         // concat K: 256 interleaved cos/sin + 64 x + 64 h + 192 gradf

typedef short bf16x8 __attribute__((ext_vector_type(8)));
typedef float f32x4  __attribute__((ext_vector_type(4)));

__device__ __forceinline__ short f2bf(float f) {
    unsigned u = __float_as_uint(f);
    u += 0x7FFF + ((u >> 16) & 1);          // round-to-nearest-even
    return (short)(u >> 16);
}
__device__ __forceinline__ float bf2f(unsigned short u) {
    return __uint_as_float(((unsigned)u) << 16);
}

// ---- workspace layout (float elements) ----
constexpr size_t OFF_XB   = 0;                                  // bf16 xB[b][n][64]
constexpr size_t OFF_PC   = OFF_XB   + (size_t)BB*NN*32;        // fp32 partial A_c (PP2 chunks)
constexpr size_t OFF_PS   = OFF_PC   + (size_t)BB*PP*CC*KK;     // fp32 partial A_s
constexpr size_t OFF_BIN4 = OFF_PC;                             // float4 binlist[b][E] (aliases pc)
constexpr size_t OFF_AC   = OFF_PS   + (size_t)BB*PP*CC*KK;     // A_c[b][i][k]
constexpr size_t OFF_AS   = OFF_AC   + (size_t)BB*CC*KK;
constexpr size_t OFF_F0   = OFF_AS   + (size_t)BB*CC*KK;        // f0[b][o]
constexpr size_t OFF_X0   = OFF_F0   + (size_t)BB*CC;           // x0[b][i]
constexpr size_t OFF_CNT  = OFF_X0   + (size_t)BB*CC;           // int counts (zeroed)
constexpr size_t OFF_OFFS = OFF_CNT  + (size_t)BB*NN;           // int offsets
constexpr size_t OFF_RANK = OFF_OFFS + (size_t)BB*NN;           // int rank[b][E]
constexpr size_t OFF_GRB  = OFF_RANK + (size_t)BB*EE;           // (unused after r5 fusion)
constexpr size_t OFF_APAN = OFF_GRB  + (size_t)BB*NN*96;        // bf16 ApanT[b][64 o][576 k]
constexpr size_t OFF_GWXT = OFF_APAN + (size_t)BB*KTOT*CC/2;    // geo_wx^T [g][i] (fp32)

// ==== k1 = fused pre-pass ∪ spectral-forward MFMA partials ====
// section order (longest-running first): k_a, edges, transpose, x0, weights
#define S_B0 (BB*PP2*4)                 // 512  k_a
#define S_B1 (S_B0 + (BB*EE)/256)       // 2560 edges
#define S_B2 (S_B1 + BB*(NN/64))        // 3072 transpose
#define S_B3 (S_B2 + BB*CC)             // 3200 x0
#define S_B4 (S_B3 + 48)                // 3248 weights
__global__ void __launch_bounds__(256) k1(const float* __restrict__ x,
                                          const float* __restrict__ nwt,
                                          const int* __restrict__ edges,
                                          const float* __restrict__ W,
                                          const float* __restrict__ gw,
                                          const float* __restrict__ geo_wx,
                                          const float* __restrict__ w2,
                                          const float* __restrict__ nodes,
                                          const float* __restrict__ modes,
                                          unsigned short* __restrict__ xB,
                                          float* __restrict__ x0,
                                          int* __restrict__ counts,
                                          int* __restrict__ rank,
                                          float* __restrict__ gwxT,
                                          short* __restrict__ ApanB,
                                          float* __restrict__ pc,
                                          float* __restrict__ ps) {
    int blk = blockIdx.x;
    int tid = threadIdx.x;
    // one shared pool, aliased per section (36352 B -> 4 blocks/CU)
    __shared__ __align__(16) char smem[36864];
    if (blk < S_B0) {
        // ---- spectral partials (k_a), 32-wide k-tile, 2 n-chunks accumulated ----
        short* Axw = (short*)smem;                     // [64 i][136] bf16
        short* Bc  = (short*)(smem + 17408);           // [32 k][136] bf16 cos
        short* Bsn = (short*)(smem + 17408 + 8704);    // [32 k][136] bf16 sin
        float* ndl = (float*)(smem + 17408 + 8704 + 8704);  // 128*3 floats
        int bc = blk;                    // [0, 512)
        int b = bc >> 8;
        int rem = bc & 255;
        int chunk2 = rem >> 2;           // [0,64)
        int kt = rem & 3;
        int k0 = kt * 32;
        int lane = tid & 63;
        int w = tid >> 6;
        int col = lane & 15;
        int quad = lane >> 4;
        int wk = w & 1;                  // k-block within 32-tile
        int wi = w >> 1;                 // i-half

        f32x4 ac[2], as4[2];
#pragma unroll
        for (int it = 0; it < 2; it++)
#pragma unroll
            for (int r = 0; r < 4; r++) { ac[it][r] = 0.f; as4[it][r] = 0.f; }

        for (int h = 0; h < 2; h++) {
            int nbase = chunk2*256 + h*128;
            if (h) __syncthreads();
            for (int e = tid; e < 128*3; e += 256) ndl[e] = nodes[((size_t)b*NN + nbase)*3 + e];
            // stage x*nw tile: 64 i x 128 n, coalesced fp32 float4 loads, pack bf16
#pragma unroll
            for (int s = 0; s < 8; s++) {
                int e = tid + s*256;
                int i = e >> 5, seg = e & 31;
                float4 xv = *(const float4*)&x[((size_t)b*CC + i)*NN + nbase + seg*4];
                float4 wv = *(const float4*)&nwt[(size_t)b*NN + nbase + seg*4];
                unsigned lo = (unsigned)(unsigned short)f2bf(xv.x*wv.x)
                            | ((unsigned)(unsigned short)f2bf(xv.y*wv.y) << 16);
                unsigned hi = (unsigned)(unsigned short)f2bf(xv.z*wv.z)
                            | ((unsigned)(unsigned short)f2bf(xv.w*wv.w) << 16);
                *(uint2*)&Axw[i*136 + seg*4] = make_uint2(lo, hi);
            }
            __syncthreads();
            // basis tile: 32 k x 128 n trig
#pragma unroll
            for (int s = 0; s < 16; s++) {
                int e = tid + s*256;
                int n = e & 127, kl = e >> 7;
                int k = k0 + kl;
                float t = ndl[n*3+0]*modes[k*3+0] + ndl[n*3+1]*modes[k*3+1]
                        + ndl[n*3+2]*modes[k*3+2];
                Bc [kl*136 + n] = f2bf(__cosf(t));
                Bsn[kl*136 + n] = f2bf(__sinf(t));
            }
            __syncthreads();

            int rowB = (wk*16 + col)*136;
#pragma unroll
            for (int ns = 0; ns < 4; ns++) {
                int koff = ns*32 + quad*8;
                bf16x8 bcf = *(bf16x8*)&Bc [rowB + koff];
                bf16x8 bsf = *(bf16x8*)&Bsn[rowB + koff];
#pragma unroll
                for (int it = 0; it < 2; it++) {
                    int itile = wi*2 + it;
                    bf16x8 af = *(bf16x8*)&Axw[(itile*16 + col)*136 + koff];
                    ac[it]  = __builtin_amdgcn_mfma_f32_16x16x32_bf16(af, bcf, ac[it], 0, 0, 0);
                    as4[it] = __builtin_amdgcn_mfma_f32_16x16x32_bf16(af, bsf, as4[it], 0, 0, 0);
                }
            }
        }
        int base = (b*PP2 + chunk2)*CC;
        int kw = k0 + wk*16 + col;
#pragma unroll
        for (int it = 0; it < 2; it++) {
#pragma unroll
            for (int r = 0; r < 4; r++) {
                int i = (wi*2 + it)*16 + quad*4 + r;
                pc[(size_t)(base + i)*KK + kw] = ac[it][r];
                ps[(size_t)(base + i)*KK + kw] = as4[it][r];
            }
        }
    } else if (blk < S_B1) {
        // ---- edge count + rank ----
        int idx = (blk - S_B0)*256 + tid;
        int tgt = edges[(size_t)idx*2 + 0];
        int b = idx / EE;
        rank[idx] = atomicAdd(&counts[b*NN + tgt], 1);
    } else if (blk < S_B2) {
        // ---- transpose ----
        float (*tile)[65] = (float (*)[65])smem;
        int tb = blk - S_B1;
        int b = tb / (NN/64);
        int n0 = (tb % (NN/64)) * 64;
        int c = tid & 63, r4 = tid >> 6;
        for (int rr = 0; rr < 16; rr++) {
            int i = r4*16 + rr;
            tile[i][c] = x[((size_t)b*CC + i)*NN + n0 + c];
        }
        __syncthreads();
        for (int rr = 0; rr < 16; rr++) {           // xB[n][i] bf16, lane c = i
            int nn = r4*16 + rr;
            xB[((size_t)b*NN + n0 + nn)*64 + c] = (unsigned short)f2bf(tile[c][nn]);
        }
    } else if (blk < S_B3) {
        // ---- x0 reduction ----
        float* red = (float*)smem;
        int bi = blk - S_B2;
        int b = bi >> 6, i = bi & 63;
        const float4* __restrict__ xr = (const float4*)&x[((size_t)b*CC + i)*NN];
        const float4* __restrict__ wr = (const float4*)&nwt[(size_t)b*NN];
        float s = 0.f;
        for (int t = tid; t < NN/4; t += 256) {
            float4 xv = xr[t];
            float4 wv = wr[t];
            s += xv.x*wv.x + xv.y*wv.y + xv.z*wv.z + xv.w*wv.w;
        }
        red[tid] = s;
        __syncthreads();
        for (int off = 128; off > 0; off >>= 1) {
            if (tid < off) red[tid] += red[tid+off];
            __syncthreads();
        }
        if (tid == 0) x0[b*CC + i] = red[0];
    } else {
        // ---- weights prep ----
        int idx = (blk - S_B3)*256 + tid;
        if (idx < CC*CC) {
            int j = idx>>6, o = idx&63;
            short wv  = f2bf(W[o*CC+j]);
            short w2v = f2bf(w2[o*CC+j]);
            ApanB[((size_t)(0*CC+o))*KTOT + 256 + j] = wv;
            ApanB[((size_t)(1*CC+o))*KTOT + 256 + j] = wv;
            ApanB[((size_t)(0*CC+o))*KTOT + 320 + j] = w2v;
            ApanB[((size_t)(1*CC+o))*KTOT + 320 + j] = w2v;
        }
        if (idx < CC*CC*DD) {
            int g = idx>>6, o = idx&63;
            short gv = f2bf(gw[o*(CC*DD)+g]);
            ApanB[((size_t)(0*CC+o))*KTOT + 384 + g] = gv;
            ApanB[((size_t)(1*CC+o))*KTOT + 384 + g] = gv;
        }
        if (idx < GG*CC) { int g = idx>>6, i = idx&63; gwxT[idx] = geo_wx[i*GG+g]; }
    }
}

// ==== k2 = partial reduction (1024 blocks, 16 thr/output) ∪ count scan (BB blocks) ====
__global__ void __launch_bounds__(256) k2(const float* __restrict__ pc, const float* __restrict__ ps,
                                          float* __restrict__ Ac, float* __restrict__ As,
                                          const int* __restrict__ counts,
                                          int* __restrict__ offsets) {
    int blk = blockIdx.x;
    int tid = threadIdx.x;
    if (blk < 1024) {
        int idx = blk*16 + (tid >> 4);      // output element in [0, BB*CC*KK=16384)
        int sub = tid & 15;
        if (idx >= BB*CC*KK) return;        // guard
        int b = idx / (CC*KK);
        int r = idx % (CC*KK);
        float sc = 0.f, ss = 0.f;
        for (int ch = sub; ch < PP2; ch += 16) {   // 4 iterations
            size_t o = ((size_t)(b*PP2 + ch)*CC)*KK + r;
            sc += pc[o]; ss += ps[o];
        }
        sc += __shfl_xor(sc, 1); sc += __shfl_xor(sc, 2);
        sc += __shfl_xor(sc, 4); sc += __shfl_xor(sc, 8);
        ss += __shfl_xor(ss, 1); ss += __shfl_xor(ss, 2);
        ss += __shfl_xor(ss, 4); ss += __shfl_xor(ss, 8);
        if (sub == 0) { Ac[idx] = sc; As[idx] = ss; }
    } else {
        // exclusive scan of counts -> offsets
        int b = blk - 1024;
        __shared__ int part[256];
        int base = b*NN + tid*64;
        int s = 0;
        for (int j = 0; j < 64; j++) s += counts[base + j];
        part[tid] = s;
        __syncthreads();
        for (int off = 1; off < 256; off <<= 1) {
            int v = (tid >= off) ? part[tid - off] : 0;
            __syncthreads();
            part[tid] += v;
            __syncthreads();
        }
        int excl = part[tid] - s;
        for (int j = 0; j < 64; j++) {
            int c = counts[base + j];
            offsets[base + j] = excl;
            excl += c;
        }
    }
}

// ==== k3 = channel mix (256 blocks) ∪ bin fill (2048 blocks) ====
__global__ void __launch_bounds__(256) k3(const float* __restrict__ Ac, const float* __restrict__ As_,
                                          const float* __restrict__ wc, const float* __restrict__ wsw,
                                          const float* __restrict__ w0, const float* __restrict__ x0,
                                          const int* __restrict__ edges, const float* __restrict__ egw,
                                          const int* __restrict__ offs, const int* __restrict__ rank,
                                          float4* __restrict__ bin4,
                                          short* __restrict__ ApanB, float* __restrict__ f0) {
    int idx = blockIdx.x;
    int tid = threadIdx.x;
    if (idx >= BB*CC*2) {
        // ---- bin fill (atomic-free: rank precomputed) ----
        int e = (idx - BB*CC*2)*256 + tid;
        int b = e / EE;
        int tgt = edges[(size_t)e*2+0];
        int src = edges[(size_t)e*2+1];
        const float* __restrict__ ew = &egw[(size_t)e*3];
        float e0 = ew[0], e1 = ew[1], e2 = ew[2];
        int pos = offs[b*NN+tgt] + rank[e];
        bin4[(size_t)b*EE + pos] = make_float4(__int_as_float(src), e0, e1, e2);
        return;
    }
    int b = idx / (CC*2);
    int rem = idx % (CC*2);
    int o = rem >> 1, khalf = rem & 1;
    int kl = tid & 63, ig = tid >> 6;
    int k = khalf*64 + kl;
    float fc = 0.f, fs = 0.f;
    for (int ii = 0; ii < 16; ii++) {
        int i = ig*16 + ii;
        float a_c = Ac[(b*CC+i)*KK + k];
        float a_s = As_[(b*CC+i)*KK + k];
        float wcc = wc[((size_t)(i*CC+o))*KK + k];
        float wss = wsw[((size_t)(i*CC+o))*KK + k];
        fc += a_c*wcc + a_s*wss;
        fs += a_c*wss - a_s*wcc;
    }
    __shared__ float rc[256], rs[256];
    __shared__ float f0s[64];
    rc[tid] = fc; rs[tid] = fs;
    if (khalf == 0 && tid < 64) f0s[tid] = x0[b*CC + tid] * w0[tid*CC + o];
    __syncthreads();
    if (ig == 0) {
        fc = rc[kl] + rc[64+kl] + rc[128+kl] + rc[192+kl];
        fs = rs[kl] + rs[64+kl] + rs[128+kl] + rs[192+kl];
        unsigned pk = (unsigned)(unsigned short)f2bf(2.f*fc)
                    | ((unsigned)(unsigned short)f2bf(-2.f*fs) << 16);
        ((unsigned*)ApanB)[((size_t)(b*CC + o))*(KTOT/2) + k] = pk;
    }
    if (khalf == 0 && tid == 0) {
        float acc = 0.f;
        for (int i = 0; i < 64; i++) acc += f0s[i];
        f0[b*CC+o] = acc;
    }
}

// ==== k_eg = edge accumulate (phase E -> LDS gradfL) ∪ final MFMA GEMM ====
// 512 threads / 8 waves per block. LDS 37.9 KB -> 4 blocks/CU -> 32 waves/CU
// (full occupancy). Phase E: 4 nodes/wave. Phase G: per-wave 16x16 output tile.
__global__ void __launch_bounds__(512, 8) k_eg(const unsigned short* __restrict__ xB,
                                               const int* __restrict__ offsets,
                                               const float4* __restrict__ bin4,
                                               const float* __restrict__ nodes,
                                               const float* __restrict__ modes,
                                               const float* __restrict__ geo,
                                               const short* __restrict__ ApanB,
                                               const float* __restrict__ f0,
                                               const float* __restrict__ wx,
                                               const float* __restrict__ gwxT,
                                               float* __restrict__ out) {
    int blk = blockIdx.x;
    int b  = blk >> 9;                 // 512 n-tiles per batch
    int n0 = (blk & 511) * 32;
    int tid = threadIdx.x;             // 0..511
    int lane = tid & 63;
    int w = tid >> 6;                  // 0..7
    int wr = w >> 1;                   // o-tile 0..3
    int wc = w & 1;                    // n-tile 0..1
    int col  = lane & 15;
    int quad = lane >> 4;              // 0..3
    int quad8 = quad * 8;
    int quad4 = quad * 4;

    // LDS layout (37764 B -> 4 blocks/CU):
    __shared__ __align__(16) char smem[37776];
    short* As = (short*)smem;                         // [64][72] bf16   @0      (9216)
    short* Bs = (short*)(smem + 9216);                // [32][72] bf16   @9216   (4608)
    short* Ws = (short*)(smem + 13824);               // [64][72] bf16   @13824  (9216)
    unsigned short* gradfL = (unsigned short*)(smem + 23040); // [3][32][72] @23040 (13824)
    float* ndl  = (float*)(smem + 36864);             // [32][3]         (384)
    float* geo3 = (float*)(smem + 37248);             // [3][32]         (384)
    int* soff   = (int*)(smem + 37632);               // [33]            (132)

    if (tid < 96) ndl[tid]  = nodes[((size_t)b*NN + n0)*3 + tid];
    if (tid < 96) geo3[tid] = geo[((size_t)b*GG + (tid >> 5))*NN + n0 + (tid & 31)];
    if (tid >= 128 && tid < 161) {
        int idx = n0 + tid - 128;
        soff[tid - 128] = (idx < NN) ? offsets[b*NN + idx] : EE;
    }
    // hoisted phase-G setup (overlaps phase-E latency)
    for (int e = tid; e < 4096; e += 512) {
        int i = e >> 6, j = e & 63;
        Ws[i*72 + j] = f2bf(wx[i*64 + j]);
    }
    f32x4 acc, xwa;
#pragma unroll
    for (int r = 0; r < 4; r++) { acc[r] = f0[b*CC + wr*16 + quad4 + r]; xwa[r] = 0.f; }
    __syncthreads();

    // ---- phase E: 8 waves x 4 nodes, direct bin4 reads, per-node scalar accum ----
    const unsigned short* __restrict__ xBb = xB + (size_t)b*NN*64 + lane;
    const float4* __restrict__ binb = bin4 + (size_t)b*EE;
    for (int q = 0; q < 4; q++) {
        int nl = w*4 + q;
        int js = soff[nl], je = soff[nl+1];
        float a0 = 0.f, a1 = 0.f, a2 = 0.f, s0 = 0.f, s1 = 0.f, s2 = 0.f;
#pragma unroll 4
        for (int j = js; j < je; j++) {
            float4 e = binb[j];
            int src = __float_as_int(e.x);
            float xs = bf2f(xBb[(size_t)src*64]);
            a0 = fmaf(xs, e.y, a0);
            a1 = fmaf(xs, e.z, a1);
            a2 = fmaf(xs, e.w, a2);
            s0 += e.y; s1 += e.z; s2 += e.w;
        }
        float xtgt = bf2f(xBb[(size_t)(n0 + nl)*64]);
        float fv0 = a0 - xtgt*s0;
        float fv1 = a1 - xtgt*s1;
        float fv2 = a2 - xtgt*s2;
        int g0 = lane*3;
        gradfL[(g0>>6)*2304 + nl*72 + (g0&63)] = (unsigned short)f2bf(fv0);
        int g1 = g0 + 1;
        gradfL[(g1>>6)*2304 + nl*72 + (g1&63)] = (unsigned short)f2bf(fv1);
        int g2 = g0 + 2;
        gradfL[(g2>>6)*2304 + nl*72 + (g2&63)] = (unsigned short)f2bf(fv2);
    }

    const short* __restrict__ Ab = ApanB + ((size_t)b*CC)*KTOT;

    for (int c = 0; c < 9; c++) {
        __syncthreads();
        // A chunk: 64 o x 64 k = 512 uint4, exactly 1 per thread
        {
            int o = tid >> 3, seg = tid & 7;
            *(uint4*)&As[o*72 + seg*8] =
                *(const uint4*)&Ab[(size_t)o*KTOT + c*64 + seg*8];
        }
        // B chunk (32 n)
        if (c < 4) {
#pragma unroll
            for (int s = 0; s < 2; s++) {
                int e = tid + s*512;              // 1024 = 32 n x 32 k-pairs
                int n = e >> 5, kpl = e & 31;
                int kp = c*32 + kpl;
                float t = ndl[n*3+0]*modes[kp*3+0] + ndl[n*3+1]*modes[kp*3+1]
                        + ndl[n*3+2]*modes[kp*3+2];
                unsigned pk = (unsigned)(unsigned short)f2bf(__cosf(t))
                            | ((unsigned)(unsigned short)f2bf(__sinf(t)) << 16);
                ((unsigned*)Bs)[n*36 + kpl] = pk;
            }
        } else if (c == 4) {
            // x tile: 32 n x 64 i = 256 uint4
            if (tid < 256) {
                int n = tid >> 3, seg = tid & 7;
                *(uint4*)&Bs[n*72 + seg*8] =
                    *(const uint4*)&xB[((size_t)(b*NN + n0 + n))*64 + seg*8];
            }
        } else if (c == 5) {
            // h tile from xwa (per-wave 16x16 region, MFMA D-layout)
            int n = wc*16 + col;
            float gv0 = geo3[n], gv1 = geo3[32+n], gv2 = geo3[64+n];
#pragma unroll
            for (int r = 0; r < 4; r++) {
                int i = wr*16 + quad4 + r;
                float t = gwxT[i]*gv0 + gwxT[64+i]*gv1 + gwxT[128+i]*gv2;
                float ssv = t / (1.f + fabsf(t));
                Bs[n*72 + i] = f2bf(ssv * xwa[r]);
            }
        }
        // c >= 6: B comes straight from gradfL (staged in phase E)
        __syncthreads();
        const short* Bbase = (c >= 6) ? (const short*)&gradfL[(size_t)(c-6)*2304] : Bs;
        int rowA = (wr*16 + col) * 72;
        int rowB = (wc*16 + col) * 72;
#pragma unroll
        for (int ko = 0; ko < 2; ko++) {
            int koff = ko*32 + quad8;
            bf16x8 af = *(bf16x8*)&As[rowA + koff];
            bf16x8 bfv = *(bf16x8*)&Bbase[rowB + koff];
            acc = __builtin_amdgcn_mfma_f32_16x16x32_bf16(af, bfv, acc, 0, 0, 0);
            if (c == 4) {
                bf16x8 wf = *(bf16x8*)&Ws[rowA + koff];
                xwa = __builtin_amdgcn_mfma_f32_16x16x32_bf16(wf, bfv, xwa, 0, 0, 0);
            }
        }
    }
#pragma unroll
    for (int r = 0; r < 4; r++) {
        int o = wr*16 + quad4 + r;
        float v = acc[r];
        float g = 0.5f * v * (1.f + erff(v * 0.70710678118654752f));
        out[((size_t)b*CC + o)*NN + n0 + wc*16 + col] = g;
    }
}

extern "C" void kernel_launch(void* const* d_in, const int* in_sizes, int n_in,
                              void* d_out, int out_size, void* d_ws, size_t ws_size,
                              hipStream_t stream) {
    const float* x      = (const float*)d_in[0];
    const float* nodes  = (const float*)d_in[1];
    const float* nwt    = (const float*)d_in[2];
    const float* geo    = (const float*)d_in[3];
    const int*   edges  = (const int*)d_in[4];
    const float* egw    = (const float*)d_in[5];
    const float* modes  = (const float*)d_in[6];
    const float* wc     = (const float*)d_in[7];
    const float* wsw    = (const float*)d_in[8];
    const float* w0     = (const float*)d_in[9];
    const float* W      = (const float*)d_in[10];
    const float* gw     = (const float*)d_in[11];
    const float* geo_wx = (const float*)d_in[12];
    const float* wx     = (const float*)d_in[13];
    const float* w2     = (const float*)d_in[14];

    float* ws   = (float*)d_ws;
    unsigned short* xB  = (unsigned short*)(ws + OFF_XB);
    float* pc   = ws + OFF_PC;
    float* ps   = ws + OFF_PS;
    float* Ac   = ws + OFF_AC;
    float* As_  = ws + OFF_AS;
    float* f0   = ws + OFF_F0;
    float* x0   = ws + OFF_X0;
    int*  counts = (int*)(ws + OFF_CNT);
    int*  offs   = (int*)(ws + OFF_OFFS);
    int*  rank   = (int*)(ws + OFF_RANK);
    float4* bin4 = (float4*)(ws + OFF_BIN4);
    short* ApanB  = (short*)(ws + OFF_APAN);
    float* gwxT   = ws + OFF_GWXT;
    float* out  = (float*)d_out;

    hipMemsetAsync(counts, 0, (size_t)(BB*NN)*sizeof(int), stream);

    k1 <<<S_B4, 256, 0, stream>>>(x, nwt, edges, W, gw, geo_wx, w2, nodes, modes,
                                  xB, x0, counts, rank, gwxT, ApanB, pc, ps);
    k2 <<<1024 + BB, 256, 0, stream>>>(pc, ps, Ac, As_, counts, offs);
    k3 <<<BB*CC*2 + (BB*EE)/256, 256, 0, stream>>>(Ac, As_, wc, wsw, w0, x0,
                                                   edges, egw, offs, rank, bin4, ApanB, f0);
    k_eg <<<BB*(NN/32), 512, 0, stream>>>(xB, offs, bin4, nodes, modes, geo,
                                          ApanB, f0, wx, gwxT, out);
}